// Round 7
// baseline (395.387 us; speedup 1.0000x reference)
//
#include <hip/hip_runtime.h>
#include <math.h>

// Problem constants (from reference)
#define NDIM 64
#define NK   128
#define ALPHA_DP 1.0
#define TAU0 0.0
#define C0v  1.0
#define N0v  ((double)(NDIM + 2))
#define B0v  1.0

#define ITERS 2          // 128-point iterations per block (grid = N/256 = 1024)
#define NSLOT 64         // ll partial-sum slots

typedef __attribute__((ext_vector_type(8))) short bf16x8;
typedef __attribute__((ext_vector_type(16))) float f32x16;
typedef __attribute__((ext_vector_type(4))) float f32x4;

// ---------------- device math helpers ----------------
__device__ double digamma_d(double x) {
    double r = 0.0;
    while (x < 6.0) { r -= 1.0 / x; x += 1.0; }
    double inv = 1.0 / x, inv2 = inv * inv;
    double s = log(x) - 0.5 * inv
        - inv2 * (1.0/12.0 - inv2 * (1.0/120.0 - inv2 * (1.0/252.0
            - inv2 * (1.0/240.0 - inv2 * (1.0/132.0)))));
    return s + r;
}

__device__ inline unsigned pack_bf16_hi(float a, float b) {
    // dword = {bf16(a) lo16, bf16(b) hi16}; truncation split
    return (__float_as_uint(a) >> 16) | (__float_as_uint(b) & 0xffff0000u);
}

// fragment-major ushort index for W tables:
// feature f (0..127: x dims then y dims), cluster k.
// layout: [s=k>>5][kc=f>>4][g=(f>>3)&1][n=k&31][j=f&7]
__device__ inline int widx(int f, int k) {
    int kc = f >> 4, g = (f >> 3) & 1, j = f & 7, s = k >> 5, n = k & 31;
    return ((s * 8 + kc) * 2 + g) * 256 + n * 8 + j;
}

// ---------------- kernel 1: cluster prep (1 block, 1024 threads) ----------------
// 8 lanes per cluster, 8 dims per lane; transcendentals lane-specialized
// (each lane: exactly 1 digamma + 1 lgamma); 8-lane shuffle reductions.
// ws: scal[2] dbl | slots[64] dbl | constk[128] f32 | Wh (32KB) | Wl (32KB)
__global__ __launch_bounds__(1024) void prep_kernel(
    const float* __restrict__ nat_u,
    const float* __restrict__ nat_v,
    const float* __restrict__ nat_tau,
    const float* __restrict__ nat_c,
    const float* __restrict__ nat_n,
    const float* __restrict__ nat_B,
    double* __restrict__ scal,
    double* __restrict__ slots,
    float* __restrict__ constk,
    unsigned short* __restrict__ Wh,
    unsigned short* __restrict__ Wl) {
    const int t = threadIdx.x;
    const int k = t >> 3;            // cluster 0..127
    const int j = t & 7;             // sub-lane within cluster
    const int D = NDIM;

    double u = (double)nat_u[k] + 1.0;
    double v = (double)nat_v[k] + 1.0;
    double c = (double)nat_c[k];
    double n = (double)nat_n[k] - (double)D - 2.0;
    double a1 = 0.5 * n;
    const double a0g = 0.5 * N0v;    // 33.0
    const double b0g = 0.5 * B0v;    // 0.5
    const double log_b0g = log(b0g);

    double s_logB = 0.0, s_t2nb = 0.0, s_nb = 0.0, s_klg = 0.0, s_kln = 0.0;

#pragma unroll
    for (int i = 0; i < 8; ++i) {
        int d = j * 8 + i;
        double tau = (double)nat_tau[k * D + d] / c;
        double B   = (double)nat_B[k * D + d] - c * tau * tau;
        double nb  = n / B;
        float wx = (float)(tau * nb);          // coefficient on x_d   (feature d)
        float wy = (float)(-0.5 * nb);         // coefficient on y_d=x_d^2-1 (feature 64+d)
        unsigned bx = __float_as_uint(wx), by = __float_as_uint(wy);
        float hx = __uint_as_float(bx & 0xffff0000u);
        float hy = __uint_as_float(by & 0xffff0000u);
        Wh[widx(d, k)]      = (unsigned short)(bx >> 16);
        Wh[widx(64 + d, k)] = (unsigned short)(by >> 16);
        Wl[widx(d, k)]      = (unsigned short)(__float_as_uint(wx - hx) >> 16);
        Wl[widx(64 + d, k)] = (unsigned short)(__float_as_uint(wy - hy) >> 16);

        double b1 = 0.5 * B;
        double lb1 = log(b1);
        s_logB += lb1;
        s_t2nb += tau * tau * nb;
        s_nb   += nb;
        s_klg  += a0g * (lb1 - log_b0g) + a1 * (b0g - b1) / b1;
        s_kln  += C0v * nb * (tau - TAU0) * (tau - TAU0);
    }

    // reduce across the 8 sub-lanes of this cluster (consecutive lanes in wave)
#pragma unroll
    for (int m = 1; m < 8; m <<= 1) {
        s_logB += __shfl_xor(s_logB, m, 64);
        s_t2nb += __shfl_xor(s_t2nb, m, 64);
        s_nb   += __shfl_xor(s_nb,   m, 64);
        s_klg  += __shfl_xor(s_klg,  m, 64);
        s_kln  += __shfl_xor(s_kln,  m, 64);
    }

    // lane-specialized transcendentals: 1 digamma + 1 lgamma per lane
    double arg1 = (j == 0) ? u : (j == 1) ? v : (j == 2) ? (u + v) : a1;
    double dg = digamma_d(arg1);
    double arg2 = (j == 4) ? u : (j == 5) ? v : (j == 6) ? (u + v)
                : (j == 7) ? a1 : a0g;
    double lg = lgamma(arg2);

    const int base = (t & 63) & ~7;  // base lane of this cluster's 8-lane group
    double dg_u   = __shfl(dg, base + 0, 64);
    double dg_v   = __shfl(dg, base + 1, 64);
    double dg_uv  = __shfl(dg, base + 2, 64);
    double dg_a1  = __shfl(dg, base + 3, 64);
    double lg_a0g = __shfl(lg, base + 0, 64);
    double lg_u   = __shfl(lg, base + 4, 64);
    double lg_v   = __shfl(lg, base + 5, 64);
    double lg_uv  = __shfl(lg, base + 6, 64);
    double lg_a1  = __shfl(lg, base + 7, 64);

    __shared__ double sh_stick[NK], sh_cp[NK], sh_kl[NK];
    if (j == 0) {
        const double LOG2PI = 1.8378770664093454836;
        double e_log_det = (double)D * dg_a1 - s_logB;
        // ck without the cross-cluster stick prefix (added below)
        double cp = dg_u - dg_uv + 0.5 * (e_log_det - (double)D * LOG2PI
                    - s_t2nb - (double)D / c - s_nb);
        // KL(Beta(u,v)||Beta(1,1)): constant term lgamma(2)-2*lgamma(1) = 0
        double kl_beta = lg_uv - lg_u - lg_v
            + (u - 1.0) * dg_u + (v - 1.0) * dg_v + (2.0 - u - v) * dg_uv;
        double kl_gamma = (double)D * ((a1 - a0g) * dg_a1 - lg_a1 + lg_a0g) + s_klg;
        double kl_norm = 0.5 * ((double)D * (log(c / C0v) + C0v / c - 1.0) + s_kln);
        sh_stick[k] = dg_v - dg_uv;
        sh_cp[k]    = cp;
        sh_kl[k]    = kl_beta + kl_gamma + kl_norm;
    }
    if (t < NSLOT) slots[t] = 0.0;   // zero ll partials (ws is poisoned)
    __syncthreads();

    if (t < NK) {
        double pre = 0.0;
        for (int q = 0; q < t; ++q) pre += sh_stick[q];   // exclusive prefix
        constk[t] = (float)(sh_cp[t] + pre);
    }
    if (t == 0) {
        double tot = 0.0;
        for (int q = 0; q < NK; ++q) tot += sh_kl[q];
        scal[1] = tot;
        scal[0] = 0.0;
    }
}

// ---------------- kernel 2: barrier-free MFMA maha + in-wave softmax ----------------
// Structural register squeeze: the K loop is reorganized from 8 feature-chunks
// (which kept all 32 x-floats live, since y-chunks 4-7 reuse dims of 0-3) into
// 4 DIM-chunks, each handling its x-feature chunk (cc) AND y-feature chunk
// (cc+4, B-offset +2048 ushorts) together. Each 8-float x slice is loaded
// (rolling 1-chunk prefetch), consumed by 24 MFMAs, then DEAD -> max-live
// ~64 AGPR acc + ~75 VGPR, fits __launch_bounds__(256,3) (cap 170) WITHOUT
// spill (rounds 1/6 spilled because xa[32]+fragment sets exceeded the cap).
// 3 waves/SIMD = 12 waves/CU; LDS 32KB (Wh) x 3 blocks = 96KB OK; Wl from
// global (L2-hot). MFMA accumulation order changes (x/y interleaved) --
// fp32-commutative up to rounding noise ~100x below the bf16-split error.
__global__ __launch_bounds__(256, 3) void maha_kernel(
    const float* __restrict__ x,
    const float* __restrict__ constk,
    const uint4* __restrict__ WhG,                 // 32 KB fragment-major
    const unsigned short* __restrict__ WlG,        // 32 KB fragment-major
    float* __restrict__ r,
    double* __restrict__ slots) {
    __shared__ __align__(16) uint4 W[2048];        // 32 KB (Wh only)
    const int tid = threadIdx.x;
#pragma unroll
    for (int i = 0; i < 8; ++i) W[i * 256 + tid] = WhG[i * 256 + tid];

    const int lane = tid & 63;
    const int w    = tid >> 6;
    const int g    = lane >> 5;
    const int m0   = lane & 31;

    // per-lane x base (row w*32+m0 of this block's tile, dim offset g*8)
    const float* xr = x + ((long)blockIdx.x * (128 * ITERS) + w * 32 + m0) * NDIM + g * 8;
    // preload it=0, cc=0 slice BEFORE the barrier (hides under staging+barrier)
    f32x4 ld0 = *(const f32x4*)(xr);
    f32x4 ld1 = *(const f32x4*)(xr + 4);

    __syncthreads();                               // only barrier in the kernel
    const unsigned short* Wh = (const unsigned short*)W;

    float ck[4];
#pragma unroll
    for (int s = 0; s < 4; ++s) ck[s] = constk[s * 32 + m0];

    double dsum = 0.0;

#pragma unroll 1
    for (int it = 0; it < ITERS; ++it) {
        const long n0 = (long)blockIdx.x * (128 * ITERS) + it * 128 + w * 32;
        const float* xi = xr + (long)it * (128 * NDIM);

        f32x16 acc[4];
#pragma unroll
        for (int s = 0; s < 4; ++s)
#pragma unroll
            for (int i = 0; i < 16; ++i) acc[s][i] = 0.f;

        // ---- K loop: 4 dim-chunks x {x-features cc, y-features cc+4} x 4 strips ----
#pragma unroll
        for (int cc = 0; cc < 4; ++cc) {
            float fx[8];
            *(f32x4*)(fx)     = ld0;
            *(f32x4*)(fx + 4) = ld1;
            // rolling prefetch: next dim-chunk, or next iteration's chunk 0
            if (cc < 3) {
                ld0 = *(const f32x4*)(xi + 16 * (cc + 1));
                ld1 = *(const f32x4*)(xi + 16 * (cc + 1) + 4);
            } else if (it + 1 < ITERS) {
                ld0 = *(const f32x4*)(xi + 128 * NDIM);
                ld1 = *(const f32x4*)(xi + 128 * NDIM + 4);
            }

            float fy[8], lx[8], ly[8];
#pragma unroll
            for (int e = 0; e < 8; ++e) fy[e] = fmaf(fx[e], fx[e], -1.0f);
#pragma unroll
            for (int e = 0; e < 8; ++e) {
                float hx = __uint_as_float(__float_as_uint(fx[e]) & 0xffff0000u);
                lx[e] = fx[e] - hx;
                float hy = __uint_as_float(__float_as_uint(fy[e]) & 0xffff0000u);
                ly[e] = fy[e] - hy;
            }
            union { bf16x8 v; unsigned d[4]; } ahx, alx, ahy, aly;
#pragma unroll
            for (int q = 0; q < 4; ++q) {
                ahx.d[q] = pack_bf16_hi(fx[2 * q], fx[2 * q + 1]);
                alx.d[q] = pack_bf16_hi(lx[2 * q], lx[2 * q + 1]);
                ahy.d[q] = pack_bf16_hi(fy[2 * q], fy[2 * q + 1]);
                aly.d[q] = pack_bf16_hi(ly[2 * q], ly[2 * q + 1]);
            }
            const int bidx = (cc * 2 + g) * 256 + m0 * 8;     // x-chunk ushort index
            __builtin_amdgcn_s_setprio(1);
#pragma unroll
            for (int s = 0; s < 4; ++s) {
                bf16x8 bhx = *(const bf16x8*)(Wh  + bidx + s * 4096);
                bf16x8 blx = *(const bf16x8*)(WlG + bidx + s * 4096);
                bf16x8 bhy = *(const bf16x8*)(Wh  + bidx + 2048 + s * 4096);
                bf16x8 bly = *(const bf16x8*)(WlG + bidx + 2048 + s * 4096);
                acc[s] = __builtin_amdgcn_mfma_f32_32x32x16_bf16(ahx.v, bhx, acc[s], 0, 0, 0);
                acc[s] = __builtin_amdgcn_mfma_f32_32x32x16_bf16(alx.v, bhx, acc[s], 0, 0, 0);
                acc[s] = __builtin_amdgcn_mfma_f32_32x32x16_bf16(ahx.v, blx, acc[s], 0, 0, 0);
                acc[s] = __builtin_amdgcn_mfma_f32_32x32x16_bf16(ahy.v, bhy, acc[s], 0, 0, 0);
                acc[s] = __builtin_amdgcn_mfma_f32_32x32x16_bf16(aly.v, bhy, acc[s], 0, 0, 0);
                acc[s] = __builtin_amdgcn_mfma_f32_32x32x16_bf16(ahy.v, bly, acc[s], 0, 0, 0);
            }
            __builtin_amdgcn_s_setprio(0);
        }

        // ---- in-wave softmax per point; C/D: col=lane&31, row=(rg&3)+8*(rg>>2)+4*g ----
#pragma unroll
        for (int rg = 0; rg < 16; ++rg) {
            float l0 = acc[0][rg] + ck[0];
            float l1 = acc[1][rg] + ck[1];
            float l2 = acc[2][rg] + ck[2];
            float l3 = acc[3][rg] + ck[3];
            float M = fmaxf(fmaxf(l0, l1), fmaxf(l2, l3));
            M = fmaxf(M, __shfl_xor(M, 1, 64));
            M = fmaxf(M, __shfl_xor(M, 2, 64));
            M = fmaxf(M, __shfl_xor(M, 4, 64));
            M = fmaxf(M, __shfl_xor(M, 8, 64));
            M = fmaxf(M, __shfl_xor(M, 16, 64));
            float e0 = __expf(l0 - M), e1 = __expf(l1 - M);
            float e2 = __expf(l2 - M), e3 = __expf(l3 - M);
            float S = (e0 + e1) + (e2 + e3);
            S += __shfl_xor(S, 1, 64);
            S += __shfl_xor(S, 2, 64);
            S += __shfl_xor(S, 4, 64);
            S += __shfl_xor(S, 8, 64);
            S += __shfl_xor(S, 16, 64);
            const float inv = __builtin_amdgcn_rcpf(S);
            const int p = (rg & 3) + 8 * (rg >> 2) + 4 * g;
            float* rp = r + (n0 + p) * (long)NK + m0;
            rp[0]  = e0 * inv;
            rp[32] = e1 * inv;
            rp[64] = e2 * inv;
            rp[96] = e3 * inv;
            dsum += (double)(M + __logf(S));   // uniform within 32-lane half
        }
    }

    // ---- ll: combine halves (each half's dsum covers its 16 pts/iter), 1 atomic/wave ----
    double d0  = __shfl(dsum, 0, 64);
    double d32 = __shfl(dsum, 32, 64);
    if (lane == 0) atomicAdd(&slots[(blockIdx.x * 4 + w) & (NSLOT - 1)], d0 + d32);
}

// ---------------- kernel 3: finalize scalar ----------------
__global__ void finalize_kernel(const double* __restrict__ scal,
                                const double* __restrict__ slots,
                                float* __restrict__ out) {
    double ll = 0.0;
    for (int i = 0; i < NSLOT; ++i) ll += slots[i];
    out[0] = (float)(scal[1] - ll);   // -elbo = kl_total - ll
}

extern "C" void kernel_launch(void* const* d_in, const int* in_sizes, int n_in,
                              void* d_out, int out_size, void* d_ws, size_t ws_size,
                              hipStream_t stream) {
    const float* x       = (const float*)d_in[0];
    const float* nat_u   = (const float*)d_in[1];
    const float* nat_v   = (const float*)d_in[2];
    const float* nat_tau = (const float*)d_in[3];
    const float* nat_c   = (const float*)d_in[4];
    const float* nat_n   = (const float*)d_in[5];
    const float* nat_B   = (const float*)d_in[6];

    const int N = in_sizes[0] / NDIM;
    float* out = (float*)d_out;

    // ws layout: scal 16B | slots 512B | constk 512B | Wh 32KB | Wl 32KB (16B-aligned)
    double* scal       = (double*)d_ws;
    double* slots      = (double*)((char*)d_ws + 16);
    float* constk      = (float*)((char*)d_ws + 16 + 512);
    unsigned short* Wh = (unsigned short*)((char*)d_ws + 1040);
    unsigned short* Wl = (unsigned short*)((char*)d_ws + 1040 + 32768);
    const uint4* WhG   = (const uint4*)((char*)d_ws + 1040);

    prep_kernel<<<1, 1024, 0, stream>>>(nat_u, nat_v, nat_tau, nat_c, nat_n, nat_B,
                                        scal, slots, constk, Wh, Wl);
    maha_kernel<<<N / (128 * ITERS), 256, 0, stream>>>(x, constk, WhG, Wl, out, slots);
    finalize_kernel<<<1, 1, 0, stream>>>(scal, slots, out + (size_t)N * NK);
}

// Round 9
// 284.893 us; speedup vs baseline: 1.3878x; 1.3878x over previous
//
#include <hip/hip_runtime.h>
#include <math.h>

// Problem constants (from reference)
#define NDIM 64
#define NK   128
#define ALPHA_DP 1.0
#define TAU0 0.0
#define C0v  1.0
#define N0v  ((double)(NDIM + 2))
#define B0v  1.0

#define ITERS 4          // 128-point iterations per block (grid = N/512 = 512)
#define NSLOT 64         // ll partial-sum slots

typedef __attribute__((ext_vector_type(8))) short bf16x8;
typedef __attribute__((ext_vector_type(16))) float f32x16;
typedef __attribute__((ext_vector_type(4))) float f32x4;

// ---------------- device math helpers ----------------
__device__ double digamma_d(double x) {
    double r = 0.0;
    while (x < 6.0) { r -= 1.0 / x; x += 1.0; }
    double inv = 1.0 / x, inv2 = inv * inv;
    double s = log(x) - 0.5 * inv
        - inv2 * (1.0/12.0 - inv2 * (1.0/120.0 - inv2 * (1.0/252.0
            - inv2 * (1.0/240.0 - inv2 * (1.0/132.0)))));
    return s + r;
}

__device__ inline unsigned pack_bf16_hi(float a, float b) {
    // dword = {bf16(a) lo16, bf16(b) hi16}; truncation split
    return (__float_as_uint(a) >> 16) | (__float_as_uint(b) & 0xffff0000u);
}

// DPP cross-lane mov (VALU pipe, no DS op). CTRL must be a compile-time
// constant (builtin requirement -> template param). 0xB1=quad xor1,
// 0x4E=quad xor2, 0x124=row_ror:4, 0x128=row_ror:8. For max/sum
// butterflies ror4/ror8 cover the 16-lane row exactly like xor4/xor8.
template <int CTRL>
__device__ inline float dpp_mov(float v) {
    return __uint_as_float((unsigned)__builtin_amdgcn_update_dpp(
        0, (int)__float_as_uint(v), CTRL, 0xF, 0xF, true));
}

// fragment-major ushort index for W tables:
// feature f (0..127: x dims then y dims), cluster k.
// layout: [s=k>>5][kc=f>>4][g=(f>>3)&1][n=k&31][j=f&7]
__device__ inline int widx(int f, int k) {
    int kc = f >> 4, g = (f >> 3) & 1, j = f & 7, s = k >> 5, n = k & 31;
    return ((s * 8 + kc) * 2 + g) * 256 + n * 8 + j;
}

// ---------------- kernel 1: cluster prep (1 block, 1024 threads) ----------------
// 8 lanes per cluster, 8 dims per lane; transcendentals lane-specialized
// (each lane: exactly 1 digamma + 1 lgamma); 8-lane shuffle reductions.
// ws: scal[2] dbl | slots[64] dbl | constk[128] f32 | Wh (32KB) | Wl (32KB)
__global__ __launch_bounds__(1024) void prep_kernel(
    const float* __restrict__ nat_u,
    const float* __restrict__ nat_v,
    const float* __restrict__ nat_tau,
    const float* __restrict__ nat_c,
    const float* __restrict__ nat_n,
    const float* __restrict__ nat_B,
    double* __restrict__ scal,
    double* __restrict__ slots,
    float* __restrict__ constk,
    unsigned short* __restrict__ Wh,
    unsigned short* __restrict__ Wl) {
    const int t = threadIdx.x;
    const int k = t >> 3;            // cluster 0..127
    const int j = t & 7;             // sub-lane within cluster
    const int D = NDIM;

    double u = (double)nat_u[k] + 1.0;
    double v = (double)nat_v[k] + 1.0;
    double c = (double)nat_c[k];
    double n = (double)nat_n[k] - (double)D - 2.0;
    double a1 = 0.5 * n;
    const double a0g = 0.5 * N0v;    // 33.0
    const double b0g = 0.5 * B0v;    // 0.5
    const double log_b0g = log(b0g);

    double s_logB = 0.0, s_t2nb = 0.0, s_nb = 0.0, s_klg = 0.0, s_kln = 0.0;

#pragma unroll
    for (int i = 0; i < 8; ++i) {
        int d = j * 8 + i;
        double tau = (double)nat_tau[k * D + d] / c;
        double B   = (double)nat_B[k * D + d] - c * tau * tau;
        double nb  = n / B;
        float wx = (float)(tau * nb);          // coefficient on x_d   (feature d)
        float wy = (float)(-0.5 * nb);         // coefficient on y_d=x_d^2-1 (feature 64+d)
        unsigned bx = __float_as_uint(wx), by = __float_as_uint(wy);
        float hx = __uint_as_float(bx & 0xffff0000u);
        float hy = __uint_as_float(by & 0xffff0000u);
        Wh[widx(d, k)]      = (unsigned short)(bx >> 16);
        Wh[widx(64 + d, k)] = (unsigned short)(by >> 16);
        Wl[widx(d, k)]      = (unsigned short)(__float_as_uint(wx - hx) >> 16);
        Wl[widx(64 + d, k)] = (unsigned short)(__float_as_uint(wy - hy) >> 16);

        double b1 = 0.5 * B;
        double lb1 = log(b1);
        s_logB += lb1;
        s_t2nb += tau * tau * nb;
        s_nb   += nb;
        s_klg  += a0g * (lb1 - log_b0g) + a1 * (b0g - b1) / b1;
        s_kln  += C0v * nb * (tau - TAU0) * (tau - TAU0);
    }

    // reduce across the 8 sub-lanes of this cluster (consecutive lanes in wave)
#pragma unroll
    for (int m = 1; m < 8; m <<= 1) {
        s_logB += __shfl_xor(s_logB, m, 64);
        s_t2nb += __shfl_xor(s_t2nb, m, 64);
        s_nb   += __shfl_xor(s_nb,   m, 64);
        s_klg  += __shfl_xor(s_klg,  m, 64);
        s_kln  += __shfl_xor(s_kln,  m, 64);
    }

    // lane-specialized transcendentals: 1 digamma + 1 lgamma per lane
    double arg1 = (j == 0) ? u : (j == 1) ? v : (j == 2) ? (u + v) : a1;
    double dg = digamma_d(arg1);
    double arg2 = (j == 4) ? u : (j == 5) ? v : (j == 6) ? (u + v)
                : (j == 7) ? a1 : a0g;
    double lg = lgamma(arg2);

    const int base = (t & 63) & ~7;  // base lane of this cluster's 8-lane group
    double dg_u   = __shfl(dg, base + 0, 64);
    double dg_v   = __shfl(dg, base + 1, 64);
    double dg_uv  = __shfl(dg, base + 2, 64);
    double dg_a1  = __shfl(dg, base + 3, 64);
    double lg_a0g = __shfl(lg, base + 0, 64);
    double lg_u   = __shfl(lg, base + 4, 64);
    double lg_v   = __shfl(lg, base + 5, 64);
    double lg_uv  = __shfl(lg, base + 6, 64);
    double lg_a1  = __shfl(lg, base + 7, 64);

    __shared__ double sh_stick[NK], sh_cp[NK], sh_kl[NK];
    if (j == 0) {
        const double LOG2PI = 1.8378770664093454836;
        double e_log_det = (double)D * dg_a1 - s_logB;
        // ck without the cross-cluster stick prefix (added below)
        double cp = dg_u - dg_uv + 0.5 * (e_log_det - (double)D * LOG2PI
                    - s_t2nb - (double)D / c - s_nb);
        // KL(Beta(u,v)||Beta(1,1)): constant term lgamma(2)-2*lgamma(1) = 0
        double kl_beta = lg_uv - lg_u - lg_v
            + (u - 1.0) * dg_u + (v - 1.0) * dg_v + (2.0 - u - v) * dg_uv;
        double kl_gamma = (double)D * ((a1 - a0g) * dg_a1 - lg_a1 + lg_a0g) + s_klg;
        double kl_norm = 0.5 * ((double)D * (log(c / C0v) + C0v / c - 1.0) + s_kln);
        sh_stick[k] = dg_v - dg_uv;
        sh_cp[k]    = cp;
        sh_kl[k]    = kl_beta + kl_gamma + kl_norm;
    }
    if (t < NSLOT) slots[t] = 0.0;   // zero ll partials (ws is poisoned)
    __syncthreads();

    if (t < NK) {
        double pre = 0.0;
        for (int q = 0; q < t; ++q) pre += sh_stick[q];   // exclusive prefix
        constk[t] = (float)(sh_cp[t] + pre);
    }
    if (t == 0) {
        double tot = 0.0;
        for (int q = 0; q < NK; ++q) tot += sh_kl[q];
        scal[1] = tot;
        scal[0] = 0.0;
    }
}

// ---------------- kernel 2: barrier-free MFMA maha + in-wave softmax ----------------
// Round-5 structure (best measured: maha ~140us): both W tables in LDS (64KB),
// ITERS=4, grid 512 (all-resident), x prefetch, setprio, (256,2) -> natural
// 128 VGPR + 64 AGPR, no spill. Occupancy is structurally 2 waves/SIMD
// (rounds 1/6/7: ANY higher launch-bounds cap makes the allocator starve the
// arch-VGPR side and spill ~130MB -- do not re-try).
// THIS ROUND: softmax reductions via DPP butterflies instead of 5-deep
// __shfl_xor (ds_bpermute) chains. Per rg: 10 DS ops -> 2 (only xor16 stays
// DS). Removes the in-order lgkmcnt serialization across the 16 rg chains,
// which the counter model says is the dominant per-wave stall (VALUBusy 13%,
// MfmaUtil 7%, 0 bank conflicts, ~84K cy/iter vs ~2K cy of issued work).
__global__ __launch_bounds__(256, 2) void maha_kernel(
    const float* __restrict__ x,
    const float* __restrict__ constk,
    const uint4* __restrict__ Wg,      // WhL then WlL, 64 KB fragment-major
    float* __restrict__ r,
    double* __restrict__ slots) {
    __shared__ __align__(16) uint4 W[4096];          // 64 KB
    const int tid = threadIdx.x;
#pragma unroll
    for (int i = 0; i < 16; ++i) W[i * 256 + tid] = Wg[i * 256 + tid];
    __syncthreads();                                  // only barrier in the kernel
    const unsigned short* Wh = (const unsigned short*)W;           // [0,32768)
    const unsigned short* Wl = (const unsigned short*)(W + 2048);  // [32768,65536)

    const int lane = tid & 63;
    const int w    = tid >> 6;
    const int g    = lane >> 5;
    const int m0   = lane & 31;

    float ck[4];
#pragma unroll
    for (int s = 0; s < 4; ++s) ck[s] = constk[s * 32 + m0];

    double dsum = 0.0;

    // this lane's x base: row (blockbase + w*32 + m0), dims {g*8+16t .. +8}
    const long xrow0 = (long)blockIdx.x * (128 * ITERS) + w * 32 + m0;
    const float* xp = x + xrow0 * NDIM + g * 8;

    // ---- prefetch it=0 (8 x 16B) ----
    f32x4 cur[8], nxt[8];
#pragma unroll
    for (int t = 0; t < 4; ++t) {
        cur[2 * t]     = *(const f32x4*)(xp + t * 16);
        cur[2 * t + 1] = *(const f32x4*)(xp + t * 16 + 4);
    }

#pragma unroll 1
    for (int it = 0; it < ITERS; ++it) {
        // ---- issue next iteration's x loads early (latency hidden under K-loop) ----
        if (it + 1 < ITERS) {
            const float* xn = xp + (long)(it + 1) * (128 * NDIM);
#pragma unroll
            for (int t = 0; t < 4; ++t) {
                nxt[2 * t]     = *(const f32x4*)(xn + t * 16);
                nxt[2 * t + 1] = *(const f32x4*)(xn + t * 16 + 4);
            }
        }

        const long n0 = (long)blockIdx.x * (128 * ITERS) + it * 128 + w * 32;

        f32x16 acc[4];
#pragma unroll
        for (int s = 0; s < 4; ++s)
#pragma unroll
            for (int i = 0; i < 16; ++i) acc[s][i] = 0.f;

        // ---- K loop: 8 chunks x 4 strips x (hh, lh, hl) ----
#pragma unroll
        for (int c = 0; c < 8; ++c) {
            float fe[8], lo[8];
#pragma unroll
            for (int e = 0; e < 8; ++e) {
                float xv = cur[(c & 3) * 2 + (e >> 2)][e & 3];
                fe[e] = (c < 4) ? xv : fmaf(xv, xv, -1.0f);   // x or y=x^2-1
            }
#pragma unroll
            for (int e = 0; e < 8; ++e) {
                float h = __uint_as_float(__float_as_uint(fe[e]) & 0xffff0000u);
                lo[e] = fe[e] - h;
            }
            union { bf16x8 v; unsigned d[4]; } ah, al;
#pragma unroll
            for (int q = 0; q < 4; ++q) {
                ah.d[q] = pack_bf16_hi(fe[2 * q], fe[2 * q + 1]);
                al.d[q] = pack_bf16_hi(lo[2 * q], lo[2 * q + 1]);
            }
            const int bidx = (c * 2 + g) * 256 + m0 * 8;      // ushort index
            __builtin_amdgcn_s_setprio(1);
#pragma unroll
            for (int s = 0; s < 4; ++s) {
                bf16x8 bh = *(const bf16x8*)(Wh + bidx + s * 4096);
                bf16x8 bl = *(const bf16x8*)(Wl + bidx + s * 4096);
                acc[s] = __builtin_amdgcn_mfma_f32_32x32x16_bf16(ah.v, bh, acc[s], 0, 0, 0);
                acc[s] = __builtin_amdgcn_mfma_f32_32x32x16_bf16(al.v, bh, acc[s], 0, 0, 0);
                acc[s] = __builtin_amdgcn_mfma_f32_32x32x16_bf16(ah.v, bl, acc[s], 0, 0, 0);
            }
            __builtin_amdgcn_s_setprio(0);
        }

        // ---- in-wave softmax per point; C/D: col=lane&31, row=(rg&3)+8*(rg>>2)+4*g ----
        // reduce domain = 32 lanes of this half: quad xor1, quad xor2,
        // row_ror4 (covers xor4), row_ror8 (covers xor8), then one DS xor16.
#pragma unroll
        for (int rg = 0; rg < 16; ++rg) {
            float l0 = acc[0][rg] + ck[0];
            float l1 = acc[1][rg] + ck[1];
            float l2 = acc[2][rg] + ck[2];
            float l3 = acc[3][rg] + ck[3];
            float M = fmaxf(fmaxf(l0, l1), fmaxf(l2, l3));
            M = fmaxf(M, dpp_mov<0xB1>(M));    // quad_perm(1,0,3,2)  xor1
            M = fmaxf(M, dpp_mov<0x4E>(M));    // quad_perm(2,3,0,1)  xor2
            M = fmaxf(M, dpp_mov<0x124>(M));   // row_ror:4
            M = fmaxf(M, dpp_mov<0x128>(M));   // row_ror:8
            M = fmaxf(M, __shfl_xor(M, 16, 64));
            float e0 = __expf(l0 - M), e1 = __expf(l1 - M);
            float e2 = __expf(l2 - M), e3 = __expf(l3 - M);
            float S = (e0 + e1) + (e2 + e3);
            S += dpp_mov<0xB1>(S);
            S += dpp_mov<0x4E>(S);
            S += dpp_mov<0x124>(S);
            S += dpp_mov<0x128>(S);
            S += __shfl_xor(S, 16, 64);
            const float inv = __builtin_amdgcn_rcpf(S);
            const int p = (rg & 3) + 8 * (rg >> 2) + 4 * g;
            float* rp = r + (n0 + p) * (long)NK + m0;
            rp[0]  = e0 * inv;
            rp[32] = e1 * inv;
            rp[64] = e2 * inv;
            rp[96] = e3 * inv;
            dsum += (double)(M + __logf(S));   // uniform within 32-lane half
        }

        // rotate prefetched x into place (compiler renames; waitcnt lands here)
        if (it + 1 < ITERS) {
#pragma unroll
            for (int q = 0; q < 8; ++q) cur[q] = nxt[q];
        }
    }

    // ---- ll: combine halves (each half's dsum covers its 16 pts/iter), 1 atomic/wave ----
    double d0  = __shfl(dsum, 0, 64);
    double d32 = __shfl(dsum, 32, 64);
    if (lane == 0) atomicAdd(&slots[(blockIdx.x * 4 + w) & (NSLOT - 1)], d0 + d32);
}

// ---------------- kernel 3: finalize scalar ----------------
__global__ void finalize_kernel(const double* __restrict__ scal,
                                const double* __restrict__ slots,
                                float* __restrict__ out) {
    double ll = 0.0;
    for (int i = 0; i < NSLOT; ++i) ll += slots[i];
    out[0] = (float)(scal[1] - ll);   // -elbo = kl_total - ll
}

extern "C" void kernel_launch(void* const* d_in, const int* in_sizes, int n_in,
                              void* d_out, int out_size, void* d_ws, size_t ws_size,
                              hipStream_t stream) {
    const float* x       = (const float*)d_in[0];
    const float* nat_u   = (const float*)d_in[1];
    const float* nat_v   = (const float*)d_in[2];
    const float* nat_tau = (const float*)d_in[3];
    const float* nat_c   = (const float*)d_in[4];
    const float* nat_n   = (const float*)d_in[5];
    const float* nat_B   = (const float*)d_in[6];

    const int N = in_sizes[0] / NDIM;
    float* out = (float*)d_out;

    // ws layout: scal 16B | slots 512B | constk 512B | Wh 32KB | Wl 32KB (16B-aligned)
    double* scal       = (double*)d_ws;
    double* slots      = (double*)((char*)d_ws + 16);
    float* constk      = (float*)((char*)d_ws + 16 + 512);
    unsigned short* Wh = (unsigned short*)((char*)d_ws + 1040);
    unsigned short* Wl = (unsigned short*)((char*)d_ws + 1040 + 32768);
    const uint4* Wg    = (const uint4*)((char*)d_ws + 1040);

    prep_kernel<<<1, 1024, 0, stream>>>(nat_u, nat_v, nat_tau, nat_c, nat_n, nat_B,
                                        scal, slots, constk, Wh, Wl);
    maha_kernel<<<N / (128 * ITERS), 256, 0, stream>>>(x, constk, Wg, out, slots);
    finalize_kernel<<<1, 1, 0, stream>>>(scal, slots, out + (size_t)N * NK);
}

// Round 10
// 223.869 us; speedup vs baseline: 1.7662x; 1.2726x over previous
//
#include <hip/hip_runtime.h>
#include <math.h>

// Problem constants (from reference)
#define NDIM 64
#define NK   128
#define ALPHA_DP 1.0
#define TAU0 0.0
#define C0v  1.0
#define N0v  ((double)(NDIM + 2))
#define B0v  1.0

#define ITERS 4          // 128-point iterations per block (grid = N/512 = 512)
#define NSLOT 64         // ll partial-sum slots

typedef __attribute__((ext_vector_type(8))) short bf16x8;
typedef __attribute__((ext_vector_type(16))) float f32x16;
typedef __attribute__((ext_vector_type(4))) float f32x4;
typedef __attribute__((ext_vector_type(2))) float f32x2;

// ---------------- device math helpers ----------------
__device__ double digamma_d(double x) {
    double r = 0.0;
    while (x < 6.0) { r -= 1.0 / x; x += 1.0; }
    double inv = 1.0 / x, inv2 = inv * inv;
    double s = log(x) - 0.5 * inv
        - inv2 * (1.0/12.0 - inv2 * (1.0/120.0 - inv2 * (1.0/252.0
            - inv2 * (1.0/240.0 - inv2 * (1.0/132.0)))));
    return s + r;
}

__device__ inline unsigned pack_bf16_hi(float a, float b) {
    // dword = {bf16(a) lo16, bf16(b) hi16}; truncation split
    return (__float_as_uint(a) >> 16) | (__float_as_uint(b) & 0xffff0000u);
}

// DPP cross-lane mov (VALU pipe, no DS op). CTRL must be a compile-time
// constant (builtin requirement -> template param). 0xB1=quad xor1,
// 0x4E=quad xor2, 0x124=row_ror:4, 0x128=row_ror:8. For max/sum
// butterflies ror4/ror8 cover the 16-lane row exactly like xor4/xor8.
template <int CTRL>
__device__ inline float dpp_mov(float v) {
    return __uint_as_float((unsigned)__builtin_amdgcn_update_dpp(
        0, (int)__float_as_uint(v), CTRL, 0xF, 0xF, true));
}

// fragment-major ushort index for W tables:
// feature f (0..127: x dims then y dims), cluster k.
// layout: [s=k>>5][kc=f>>4][g=(f>>3)&1][n=k&31][j=f&7]
__device__ inline int widx(int f, int k) {
    int kc = f >> 4, g = (f >> 3) & 1, j = f & 7, s = k >> 5, n = k & 31;
    return ((s * 8 + kc) * 2 + g) * 256 + n * 8 + j;
}

// ---------------- kernel 1: cluster prep (1 block, 1024 threads) ----------------
__global__ __launch_bounds__(1024) void prep_kernel(
    const float* __restrict__ nat_u,
    const float* __restrict__ nat_v,
    const float* __restrict__ nat_tau,
    const float* __restrict__ nat_c,
    const float* __restrict__ nat_n,
    const float* __restrict__ nat_B,
    double* __restrict__ scal,
    double* __restrict__ slots,
    float* __restrict__ constk,
    unsigned short* __restrict__ Wh,
    unsigned short* __restrict__ Wl) {
    const int t = threadIdx.x;
    const int k = t >> 3;            // cluster 0..127
    const int j = t & 7;             // sub-lane within cluster
    const int D = NDIM;

    double u = (double)nat_u[k] + 1.0;
    double v = (double)nat_v[k] + 1.0;
    double c = (double)nat_c[k];
    double n = (double)nat_n[k] - (double)D - 2.0;
    double a1 = 0.5 * n;
    const double a0g = 0.5 * N0v;    // 33.0
    const double b0g = 0.5 * B0v;    // 0.5
    const double log_b0g = log(b0g);

    double s_logB = 0.0, s_t2nb = 0.0, s_nb = 0.0, s_klg = 0.0, s_kln = 0.0;

#pragma unroll
    for (int i = 0; i < 8; ++i) {
        int d = j * 8 + i;
        double tau = (double)nat_tau[k * D + d] / c;
        double B   = (double)nat_B[k * D + d] - c * tau * tau;
        double nb  = n / B;
        float wx = (float)(tau * nb);          // coefficient on x_d   (feature d)
        float wy = (float)(-0.5 * nb);         // coefficient on y_d=x_d^2-1 (feature 64+d)
        unsigned bx = __float_as_uint(wx), by = __float_as_uint(wy);
        float hx = __uint_as_float(bx & 0xffff0000u);
        float hy = __uint_as_float(by & 0xffff0000u);
        Wh[widx(d, k)]      = (unsigned short)(bx >> 16);
        Wh[widx(64 + d, k)] = (unsigned short)(by >> 16);
        Wl[widx(d, k)]      = (unsigned short)(__float_as_uint(wx - hx) >> 16);
        Wl[widx(64 + d, k)] = (unsigned short)(__float_as_uint(wy - hy) >> 16);

        double b1 = 0.5 * B;
        double lb1 = log(b1);
        s_logB += lb1;
        s_t2nb += tau * tau * nb;
        s_nb   += nb;
        s_klg  += a0g * (lb1 - log_b0g) + a1 * (b0g - b1) / b1;
        s_kln  += C0v * nb * (tau - TAU0) * (tau - TAU0);
    }

    // reduce across the 8 sub-lanes of this cluster (consecutive lanes in wave)
#pragma unroll
    for (int m = 1; m < 8; m <<= 1) {
        s_logB += __shfl_xor(s_logB, m, 64);
        s_t2nb += __shfl_xor(s_t2nb, m, 64);
        s_nb   += __shfl_xor(s_nb,   m, 64);
        s_klg  += __shfl_xor(s_klg,  m, 64);
        s_kln  += __shfl_xor(s_kln,  m, 64);
    }

    // lane-specialized transcendentals: 1 digamma + 1 lgamma per lane
    double arg1 = (j == 0) ? u : (j == 1) ? v : (j == 2) ? (u + v) : a1;
    double dg = digamma_d(arg1);
    double arg2 = (j == 4) ? u : (j == 5) ? v : (j == 6) ? (u + v)
                : (j == 7) ? a1 : a0g;
    double lg = lgamma(arg2);

    const int base = (t & 63) & ~7;  // base lane of this cluster's 8-lane group
    double dg_u   = __shfl(dg, base + 0, 64);
    double dg_v   = __shfl(dg, base + 1, 64);
    double dg_uv  = __shfl(dg, base + 2, 64);
    double dg_a1  = __shfl(dg, base + 3, 64);
    double lg_a0g = __shfl(lg, base + 0, 64);
    double lg_u   = __shfl(lg, base + 4, 64);
    double lg_v   = __shfl(lg, base + 5, 64);
    double lg_uv  = __shfl(lg, base + 6, 64);
    double lg_a1  = __shfl(lg, base + 7, 64);

    __shared__ double sh_stick[NK], sh_cp[NK], sh_kl[NK];
    if (j == 0) {
        const double LOG2PI = 1.8378770664093454836;
        double e_log_det = (double)D * dg_a1 - s_logB;
        // ck without the cross-cluster stick prefix (added below)
        double cp = dg_u - dg_uv + 0.5 * (e_log_det - (double)D * LOG2PI
                    - s_t2nb - (double)D / c - s_nb);
        // KL(Beta(u,v)||Beta(1,1)): constant term lgamma(2)-2*lgamma(1) = 0
        double kl_beta = lg_uv - lg_u - lg_v
            + (u - 1.0) * dg_u + (v - 1.0) * dg_v + (2.0 - u - v) * dg_uv;
        double kl_gamma = (double)D * ((a1 - a0g) * dg_a1 - lg_a1 + lg_a0g) + s_klg;
        double kl_norm = 0.5 * ((double)D * (log(c / C0v) + C0v / c - 1.0) + s_kln);
        sh_stick[k] = dg_v - dg_uv;
        sh_cp[k]    = cp;
        sh_kl[k]    = kl_beta + kl_gamma + kl_norm;
    }
    if (t < NSLOT) slots[t] = 0.0;   // zero ll partials (ws is poisoned)
    __syncthreads();

    if (t < NK) {
        double pre = 0.0;
        for (int q = 0; q < t; ++q) pre += sh_stick[q];   // exclusive prefix
        constk[t] = (float)(sh_cp[t] + pre);
    }
    if (t == 0) {
        double tot = 0.0;
        for (int q = 0; q < NK; ++q) tot += sh_kl[q];
        scal[1] = tot;
        scal[0] = 0.0;
    }
}

// ---------------- kernel 2: barrier-free MFMA maha + in-wave softmax ----------------
// Round-9 structure (best: 284.9us total, maha ~128us): W in LDS (64KB),
// ITERS=4, grid 512, x prefetch, setprio, DPP softmax butterflies, (256,2)
// natural 128 VGPR + 64 AGPR (register-capped at 2 waves/SIMD; do NOT raise
// launch-bounds -- rounds 1/6/7 all spilled).
// THIS ROUND: full-row r stores via per-wave LDS transpose staging.
// Old stores: 4x dword per half-wave = 128B segments; the two g-halves hit
// DIFFERENT rows, so no instruction ever covered more than 128B contiguous.
// Counters show FETCH = x + ~rsize (195MB vs 67 ideal) and WRITE = 1.58x r:
// L2 read-for-ownership RMW on partial-line stores, backpressuring the store
// queue (the latency stall that keeps maha at 128us regardless of traffic).
// New path per rg: 4 conflict-free ds_write_b32 -> 2 ds_read_b64 -> 2
// global_store_dwordx2 where 64 lanes cover one FULL 512B row per instruction.
__global__ __launch_bounds__(256, 2) void maha_kernel(
    const float* __restrict__ x,
    const float* __restrict__ constk,
    const uint4* __restrict__ Wg,      // WhL then WlL, 64 KB fragment-major
    float* __restrict__ r,
    double* __restrict__ slots) {
    __shared__ __align__(16) uint4 W[4096];          // 64 KB
    __shared__ __align__(16) float SB[4 * 512];      // 8 KB store-transpose staging
    const int tid = threadIdx.x;
#pragma unroll
    for (int i = 0; i < 16; ++i) W[i * 256 + tid] = Wg[i * 256 + tid];
    __syncthreads();                                  // only barrier in the kernel
    const unsigned short* Wh = (const unsigned short*)W;           // [0,32768)
    const unsigned short* Wl = (const unsigned short*)(W + 2048);  // [32768,65536)

    const int lane = tid & 63;
    const int w    = tid >> 6;
    const int g    = lane >> 5;
    const int m0   = lane & 31;
    float* sbw = SB + w * 512;        // this wave's 2x 256-float buffers

    float ck[4];
#pragma unroll
    for (int s = 0; s < 4; ++s) ck[s] = constk[s * 32 + m0];

    double dsum = 0.0;

    // this lane's x base: row (blockbase + w*32 + m0), dims {g*8+16t .. +8}
    const long xrow0 = (long)blockIdx.x * (128 * ITERS) + w * 32 + m0;
    const float* xp = x + xrow0 * NDIM + g * 8;

    // ---- prefetch it=0 (8 x 16B) ----
    f32x4 cur[8], nxt[8];
#pragma unroll
    for (int t = 0; t < 4; ++t) {
        cur[2 * t]     = *(const f32x4*)(xp + t * 16);
        cur[2 * t + 1] = *(const f32x4*)(xp + t * 16 + 4);
    }

#pragma unroll 1
    for (int it = 0; it < ITERS; ++it) {
        // ---- issue next iteration's x loads early (latency hidden under K-loop) ----
        if (it + 1 < ITERS) {
            const float* xn = xp + (long)(it + 1) * (128 * NDIM);
#pragma unroll
            for (int t = 0; t < 4; ++t) {
                nxt[2 * t]     = *(const f32x4*)(xn + t * 16);
                nxt[2 * t + 1] = *(const f32x4*)(xn + t * 16 + 4);
            }
        }

        const long n0 = (long)blockIdx.x * (128 * ITERS) + it * 128 + w * 32;

        f32x16 acc[4];
#pragma unroll
        for (int s = 0; s < 4; ++s)
#pragma unroll
            for (int i = 0; i < 16; ++i) acc[s][i] = 0.f;

        // ---- K loop: 8 chunks x 4 strips x (hh, lh, hl) ----
#pragma unroll
        for (int c = 0; c < 8; ++c) {
            float fe[8], lo[8];
#pragma unroll
            for (int e = 0; e < 8; ++e) {
                float xv = cur[(c & 3) * 2 + (e >> 2)][e & 3];
                fe[e] = (c < 4) ? xv : fmaf(xv, xv, -1.0f);   // x or y=x^2-1
            }
#pragma unroll
            for (int e = 0; e < 8; ++e) {
                float h = __uint_as_float(__float_as_uint(fe[e]) & 0xffff0000u);
                lo[e] = fe[e] - h;
            }
            union { bf16x8 v; unsigned d[4]; } ah, al;
#pragma unroll
            for (int q = 0; q < 4; ++q) {
                ah.d[q] = pack_bf16_hi(fe[2 * q], fe[2 * q + 1]);
                al.d[q] = pack_bf16_hi(lo[2 * q], lo[2 * q + 1]);
            }
            const int bidx = (c * 2 + g) * 256 + m0 * 8;      // ushort index
            __builtin_amdgcn_s_setprio(1);
#pragma unroll
            for (int s = 0; s < 4; ++s) {
                bf16x8 bh = *(const bf16x8*)(Wh + bidx + s * 4096);
                bf16x8 bl = *(const bf16x8*)(Wl + bidx + s * 4096);
                acc[s] = __builtin_amdgcn_mfma_f32_32x32x16_bf16(ah.v, bh, acc[s], 0, 0, 0);
                acc[s] = __builtin_amdgcn_mfma_f32_32x32x16_bf16(al.v, bh, acc[s], 0, 0, 0);
                acc[s] = __builtin_amdgcn_mfma_f32_32x32x16_bf16(ah.v, bl, acc[s], 0, 0, 0);
            }
            __builtin_amdgcn_s_setprio(0);
        }

        // ---- in-wave softmax per point; C/D: col=lane&31, row=(rg&3)+8*(rg>>2)+4*g ----
        // DPP butterflies over the 32-lane half; one DS xor16 completes it.
        // Store path: stage both rows (p0 = g=0's row, p1 = p0+4 = g=1's row)
        // in LDS, read back 8B/lane, store full 512B rows (64 lanes x 8B).
#pragma unroll
        for (int rg = 0; rg < 16; ++rg) {
            float l0 = acc[0][rg] + ck[0];
            float l1 = acc[1][rg] + ck[1];
            float l2 = acc[2][rg] + ck[2];
            float l3 = acc[3][rg] + ck[3];
            float M = fmaxf(fmaxf(l0, l1), fmaxf(l2, l3));
            M = fmaxf(M, dpp_mov<0xB1>(M));    // quad_perm(1,0,3,2)  xor1
            M = fmaxf(M, dpp_mov<0x4E>(M));    // quad_perm(2,3,0,1)  xor2
            M = fmaxf(M, dpp_mov<0x124>(M));   // row_ror:4
            M = fmaxf(M, dpp_mov<0x128>(M));   // row_ror:8
            M = fmaxf(M, __shfl_xor(M, 16, 64));
            float e0 = __expf(l0 - M), e1 = __expf(l1 - M);
            float e2 = __expf(l2 - M), e3 = __expf(l3 - M);
            float S = (e0 + e1) + (e2 + e3);
            S += dpp_mov<0xB1>(S);
            S += dpp_mov<0x4E>(S);
            S += dpp_mov<0x124>(S);
            S += dpp_mov<0x128>(S);
            S += __shfl_xor(S, 16, 64);
            const float inv = __builtin_amdgcn_rcpf(S);

            // stage: half g writes its row into floats [g*128, g*128+128)
            float* sb = sbw + (rg & 1) * 256;
            sb[(g << 7) + m0]      = e0 * inv;
            sb[(g << 7) + m0 + 32] = e1 * inv;
            sb[(g << 7) + m0 + 64] = e2 * inv;
            sb[(g << 7) + m0 + 96] = e3 * inv;
            // transpose-read: each lane takes 8B of each row (conflict-free)
            f32x2 v0 = *(const f32x2*)(sb + lane * 2);
            f32x2 v1 = *(const f32x2*)(sb + 128 + lane * 2);
            const int p0 = (rg & 3) + 8 * (rg >> 2);          // g=0 row; g=1 = p0+4
            float* rp0 = r + (n0 + p0) * (long)NK;
            *(f32x2*)(rp0 + lane * 2)                 = v0;   // full 512B row
            *(f32x2*)(rp0 + 4 * (long)NK + lane * 2)  = v1;   // full 512B row
            dsum += (double)(M + __logf(S));   // uniform within 32-lane half
        }

        // rotate prefetched x into place (compiler renames; waitcnt lands here)
        if (it + 1 < ITERS) {
#pragma unroll
            for (int q = 0; q < 8; ++q) cur[q] = nxt[q];
        }
    }

    // ---- ll: combine halves (each half's dsum covers its 16 pts/iter), 1 atomic/wave ----
    double d0  = __shfl(dsum, 0, 64);
    double d32 = __shfl(dsum, 32, 64);
    if (lane == 0) atomicAdd(&slots[(blockIdx.x * 4 + w) & (NSLOT - 1)], d0 + d32);
}

// ---------------- kernel 3: finalize scalar ----------------
__global__ void finalize_kernel(const double* __restrict__ scal,
                                const double* __restrict__ slots,
                                float* __restrict__ out) {
    double ll = 0.0;
    for (int i = 0; i < NSLOT; ++i) ll += slots[i];
    out[0] = (float)(scal[1] - ll);   // -elbo = kl_total - ll
}

extern "C" void kernel_launch(void* const* d_in, const int* in_sizes, int n_in,
                              void* d_out, int out_size, void* d_ws, size_t ws_size,
                              hipStream_t stream) {
    const float* x       = (const float*)d_in[0];
    const float* nat_u   = (const float*)d_in[1];
    const float* nat_v   = (const float*)d_in[2];
    const float* nat_tau = (const float*)d_in[3];
    const float* nat_c   = (const float*)d_in[4];
    const float* nat_n   = (const float*)d_in[5];
    const float* nat_B   = (const float*)d_in[6];

    const int N = in_sizes[0] / NDIM;
    float* out = (float*)d_out;

    // ws layout: scal 16B | slots 512B | constk 512B | Wh 32KB | Wl 32KB (16B-aligned)
    double* scal       = (double*)d_ws;
    double* slots      = (double*)((char*)d_ws + 16);
    float* constk      = (float*)((char*)d_ws + 16 + 512);
    unsigned short* Wh = (unsigned short*)((char*)d_ws + 1040);
    unsigned short* Wl = (unsigned short*)((char*)d_ws + 1040 + 32768);
    const uint4* Wg    = (const uint4*)((char*)d_ws + 1040);

    prep_kernel<<<1, 1024, 0, stream>>>(nat_u, nat_v, nat_tau, nat_c, nat_n, nat_B,
                                        scal, slots, constk, Wh, Wl);
    maha_kernel<<<N / (128 * ITERS), 256, 0, stream>>>(x, constk, Wg, out, slots);
    finalize_kernel<<<1, 1, 0, stream>>>(scal, slots, out + (size_t)N * NK);
}